// Round 5
// baseline (202.324 us; speedup 1.0000x reference)
//
#include <hip/hip_runtime.h>
#include <hip/hip_bf16.h>
#include <math.h>

typedef __attribute__((ext_vector_type(8))) __bf16 bf16x8;
typedef __attribute__((ext_vector_type(4))) float f32x4;

__device__ __forceinline__ float sigmoid_f(float v) {
  return __builtin_amdgcn_rcpf(1.f + __expf(-v));
}
__device__ __forceinline__ float tanh_f(float z) {
  float az = fabsf(z);
  float e = __expf(-2.f * az);
  float t = (1.f - e) * __builtin_amdgcn_rcpf(1.f + e);
  return copysignf(t, z);
}
__device__ __forceinline__ bf16x8 cvt8(float4 a, float4 b) {
  bf16x8 r;
  r[0] = (__bf16)a.x; r[1] = (__bf16)a.y; r[2] = (__bf16)a.z; r[3] = (__bf16)a.w;
  r[4] = (__bf16)b.x; r[5] = (__bf16)b.y; r[6] = (__bf16)b.z; r[7] = (__bf16)b.w;
  return r;
}

// Pack W_x/W_h fp32 -> bf16 into 12 half-matrix blocks of 16KB (col-half ch
// major, then pass m). 16B chunk id t = (ch*6 + m)*1024 + c2,
// c2 = (nt*4+kt)*64 + lane. Chunk holds
// W[ro + ch*64 + nt*16 + (lane&15)][kt*32 + (lane>>4)*8 .. +7].
// One col-half (6 half-matrices, 96KB) is a single contiguous run, staged
// linearly by global_load_lds; ds_read_b128 B-frag reads are wave-linear
// against the same order -> 0 bank conflicts.
// pass order m: 0 Wx_r, 1 Wh_r, 2 Wh_h, 3 Wx_h, 4 Wx_u, 5 Wh_u
__global__ void pack_weights_kernel(const float* __restrict__ Wx,
                                    const float* __restrict__ Wh,
                                    unsigned short* __restrict__ wp) {
  int t = blockIdx.x * 256 + threadIdx.x;
  if (t >= 12288) return;          // 2 halves * 6 matrices * 1024 chunks
  int ch = t / 6144;
  int r  = t - ch * 6144;
  int m  = r >> 10;
  int c2 = r & 1023;
  int nt = c2 >> 8;
  int kt = (c2 >> 6) & 3;
  int lane = c2 & 63;
  const float* src; int ro;
  switch (m) {
    case 0: src = Wx; ro = 128; break;
    case 1: src = Wh; ro = 128; break;
    case 2: src = Wh; ro = 256; break;
    case 3: src = Wx; ro = 256; break;
    case 4: src = Wx; ro = 0;   break;
    default: src = Wh; ro = 0;  break;
  }
  const float* p = src + (ro + ch * 64 + nt * 16 + (lane & 15)) * 128
                       + kt * 32 + (lane >> 4) * 8;
  *(bf16x8*)(wp + t * 8) = cvt8(*(const float4*)p, *(const float4*)(p + 4));
}

// 256 threads = 4 waves, 1 block/CU (96KB LDS), block owns 256 rows.
// Per col-half: stage all 6 half-matrices ONCE, then 4 row-chunks of 64 rows
// with zero barriers (weights resident, x/h prefetched a chunk ahead).
// 3 __syncthreads per block total.
__global__ __launch_bounds__(256, 1) void augru_kernel(
    const float* __restrict__ x, const float* __restrict__ hp,
    const float* __restrict__ att, const unsigned short* __restrict__ wp,
    const float* __restrict__ bx, const float* __restrict__ bh,
    float* __restrict__ out) {
  extern __shared__ unsigned short wlds[];  // 96 KB = 49152 shorts
  const int tid  = threadIdx.x;
  const int wave = tid >> 6;
  const int lane = tid & 63;
  const int quad = lane >> 4;
  const int l15  = lane & 15;
  const int row0 = blockIdx.x * 256;  // block's 256 rows

  // stage one col-half's 6 half-matrices (96KB): 24 rounds x 256 thr x 16B
  auto stage = [&](int ch) {
#pragma unroll
    for (int i = 0; i < 24; ++i) {
      const unsigned short* g = wp + ch * 49152 + (i * 256 + tid) * 8;
      unsigned short* l = &wlds[(i * 256 + wave * 64) * 8];  // HW adds lane*16B
      __builtin_amdgcn_global_load_lds(
          (const __attribute__((address_space(1))) void*)g,
          (__attribute__((address_space(3))) void*)l, 16, 0, 0);
    }
  };

  // raw fp32 prefetch regs for one chunk (this wave's 16 rows, full K=128)
  float4 rawx[8], rawh[8];
  auto issue_loads = [&](int c) {
    const float* xr = x  + (row0 + c * 64 + wave * 16 + l15) * 128;
    const float* hr = hp + (row0 + c * 64 + wave * 16 + l15) * 128;
#pragma unroll
    for (int kt = 0; kt < 4; ++kt) {
      int off = kt * 32 + quad * 8;
      rawx[2 * kt]     = *(const float4*)(xr + off);
      rawx[2 * kt + 1] = *(const float4*)(xr + off + 4);
      rawh[2 * kt]     = *(const float4*)(hr + off);
      rawh[2 * kt + 1] = *(const float4*)(hr + off + 4);
    }
  };

  // one half-matrix gemm-unit: 16 ds_read_b128 + 16 MFMA, wave-linear
  auto gemm = [&](int m, const bf16x8 (&af)[4], f32x4 (&acc)[4]) {
#pragma unroll
    for (int nt = 0; nt < 4; ++nt)
#pragma unroll
      for (int kt = 0; kt < 4; ++kt) {
        bf16x8 bfrag = *(const bf16x8*)&wlds[m * 8192 + ((nt * 4 + kt) * 64 + lane) * 8];
        acc[nt] = __builtin_amdgcn_mfma_f32_16x16x32_bf16(af[kt], bfrag, acc[nt], 0, 0, 0);
      }
  };

  // process 4 chunks of one col-half; weights resident, no barriers inside
  auto run_half = [&](int cb, bool last_half) {
    float br[4], bhh[4], bxh[4], bu[4];
#pragma unroll
    for (int nt = 0; nt < 4; ++nt) {
      int col = cb + nt * 16 + l15;
      br[nt]  = bx[128 + col] + bh[128 + col];
      bhh[nt] = bh[256 + col];
      bxh[nt] = bx[256 + col];
      bu[nt]  = bx[col] + bh[col];
    }
#pragma unroll 1
    for (int c = 0; c < 4; ++c) {
      // convert current chunk's raw fp32 -> bf16 MFMA A-frags
      bf16x8 xf[4], hf[4];
#pragma unroll
      for (int kt = 0; kt < 4; ++kt) {
        xf[kt] = cvt8(*(float4*)&rawx[2 * kt], *(float4*)&rawx[2 * kt + 1]);
        hf[kt] = cvt8(*(float4*)&rawh[2 * kt], *(float4*)&rawh[2 * kt + 1]);
      }
      const int rbase = row0 + c * 64 + wave * 16;
      float atts[4];
#pragma unroll
      for (int r = 0; r < 4; ++r) atts[r] = att[rbase + quad * 4 + r];
      // prefetch next chunk (or next half's chunk 0); lands during gemms
      if (!(last_half && c == 3)) issue_loads((c + 1) & 3);

      f32x4 acc[4], keep[4];
#pragma unroll
      for (int nt = 0; nt < 4; ++nt) acc[nt] = (f32x4)0.f;

      // r-gate
      gemm(0, xf, acc);
      gemm(1, hf, acc);
#pragma unroll
      for (int nt = 0; nt < 4; ++nt)
#pragma unroll
        for (int r = 0; r < 4; ++r) {
          keep[nt][r] = sigmoid_f(acc[nt][r] + br[nt]);
          acc[nt][r] = 0.f;
        }
      // t = r * (h.Wh_h + bh_h)
      gemm(2, hf, acc);
#pragma unroll
      for (int nt = 0; nt < 4; ++nt)
#pragma unroll
        for (int r = 0; r < 4; ++r) {
          keep[nt][r] = keep[nt][r] * (acc[nt][r] + bhh[nt]);
          acc[nt][r] = 0.f;
        }
      // h_tilde = tanh(x.Wx_h + bx_h + t)
      gemm(3, xf, acc);
#pragma unroll
      for (int nt = 0; nt < 4; ++nt)
#pragma unroll
        for (int r = 0; r < 4; ++r) {
          keep[nt][r] = tanh_f(acc[nt][r] + bxh[nt] + keep[nt][r]);
          acc[nt][r] = 0.f;
        }
      // u-gate
      gemm(4, xf, acc);
      gemm(5, hf, acc);
      // blend + store
#pragma unroll
      for (int nt = 0; nt < 4; ++nt) {
        int col = cb + nt * 16 + l15;
#pragma unroll
        for (int r = 0; r < 4; ++r) {
          int row = rbase + quad * 4 + r;
          float u  = sigmoid_f(acc[nt][r] + bu[nt]);
          float ua = atts[r] * u;
          float h0 = hp[row * 128 + col];
          out[row * 128 + col] = fmaf(ua, keep[nt][r] - h0, h0);  // (1-ua)*h0+ua*ht
        }
      }
    }
  };

  stage(0);        // 96KB staging in flight...
  issue_loads(0);  // ...overlapped with chunk-0 x/h loads
  asm volatile("s_waitcnt vmcnt(0)" ::: "memory");
  __syncthreads();

  run_half(0, false);   // col-half 0; chunk 3 prefetches half-1 chunk 0

  __syncthreads();      // all waves done reading half-0 weights
  stage(1);
  asm volatile("s_waitcnt vmcnt(0)" ::: "memory");
  __syncthreads();

  run_half(64, true);   // col-half 1
}

extern "C" void kernel_launch(void* const* d_in, const int* in_sizes, int n_in,
                              void* d_out, int out_size, void* d_ws, size_t ws_size,
                              hipStream_t stream) {
  const float* x   = (const float*)d_in[0];
  const float* hpv = (const float*)d_in[1];
  const float* att = (const float*)d_in[2];
  const float* Wx  = (const float*)d_in[3];
  const float* bx  = (const float*)d_in[4];
  const float* Wh  = (const float*)d_in[5];
  const float* bh  = (const float*)d_in[6];
  float* out = (float*)d_out;
  unsigned short* wp = (unsigned short*)d_ws;  // 196,608 B of scratch

  pack_weights_kernel<<<48, 256, 0, stream>>>(Wx, Wh, wp);
  augru_kernel<<<256, 256, 98304, stream>>>(x, hpv, att, wp, bx, bh, out);
}

// Round 6
// 130.879 us; speedup vs baseline: 1.5459x; 1.5459x over previous
//
#include <hip/hip_runtime.h>
#include <hip/hip_bf16.h>
#include <math.h>

typedef __attribute__((ext_vector_type(8))) __bf16 bf16x8;
typedef __attribute__((ext_vector_type(4))) float f32x4;

__device__ __forceinline__ float sigmoid_f(float v) {
  return __builtin_amdgcn_rcpf(1.f + __expf(-v));
}
__device__ __forceinline__ float tanh_f(float z) {
  float az = fabsf(z);
  float e = __expf(-2.f * az);
  float t = (1.f - e) * __builtin_amdgcn_rcpf(1.f + e);
  return copysignf(t, z);
}
__device__ __forceinline__ bf16x8 cvt8(float4 a, float4 b) {
  bf16x8 r;
  r[0] = (__bf16)a.x; r[1] = (__bf16)a.y; r[2] = (__bf16)a.z; r[3] = (__bf16)a.w;
  r[4] = (__bf16)b.x; r[5] = (__bf16)b.y; r[6] = (__bf16)b.z; r[7] = (__bf16)b.w;
  return r;
}

// Pack W_x/W_h fp32 -> bf16 into 12 half-matrix blocks of 16KB, index (ch*6+m).
// NEW m-order pairs matrices by A-operand so phase 0 needs only xf:
//   m: 0 Wx_r, 1 Wx_h, 2 Wh_r, 3 Wh_h, 4 Wx_u, 5 Wh_u
// Phase sp stages pair {2sp, 2sp+1} = 32KB contiguous.
// 16B chunk c2 = (nt*4+kt)*64 + lane holds
//   W[ro + ch*64 + nt*16 + (lane&15)][kt*32 + (lane>>4)*8 .. +7].
// global_load_lds staging (wave-uniform base + lane*16) lands exactly where the
// ds_read_b128 B-frag reads expect it: both wave-linear, 0 bank conflicts.
__global__ void pack_weights_kernel(const float* __restrict__ Wx,
                                    const float* __restrict__ Wh,
                                    unsigned short* __restrict__ wp) {
  int t = blockIdx.x * 256 + threadIdx.x;
  if (t >= 12288) return;          // 2 halves * 6 matrices * 1024 chunks
  int ch = t / 6144;
  int r  = t - ch * 6144;
  int m  = r >> 10;
  int c2 = r & 1023;
  int nt = c2 >> 8;
  int kt = (c2 >> 6) & 3;
  int lane = c2 & 63;
  const float* src; int ro;
  switch (m) {
    case 0: src = Wx; ro = 128; break;   // Wx_r
    case 1: src = Wx; ro = 256; break;   // Wx_h
    case 2: src = Wh; ro = 128; break;   // Wh_r
    case 3: src = Wh; ro = 256; break;   // Wh_h
    case 4: src = Wx; ro = 0;   break;   // Wx_u
    default: src = Wh; ro = 0;  break;   // Wh_u
  }
  const float* p = src + (ro + ch * 64 + nt * 16 + (lane & 15)) * 128
                       + kt * 32 + (lane >> 4) * 8;
  *(bf16x8*)(wp + t * 8) = cvt8(*(const float4*)p, *(const float4*)(p + 4));
}

// 256 threads = 4 waves, wave owns 16 rows. 6 phases of 32KB (2 half-matrices,
// same A-operand pairing), double-buffered in 64KB LDS, 1 fence per phase.
// hf loads deferred into phase 0 (spreads the input burst); col-half order
// alternates by block parity (decorrelates the convoy).
__global__ __launch_bounds__(256, 2) void augru_kernel(
    const float* __restrict__ x, const float* __restrict__ hp,
    const float* __restrict__ att, const unsigned short* __restrict__ wp,
    const float* __restrict__ bx, const float* __restrict__ bh,
    float* __restrict__ out) {
  __shared__ __align__(16) unsigned short wlds[2][16384];  // 2 x 32KB
  const int tid  = threadIdx.x;
  const int wave = tid >> 6;
  const int lane = tid & 63;
  const int quad = lane >> 4;
  const int l15  = lane & 15;
  const int rb   = blockIdx.x * 64 + wave * 16;  // this wave's 16 rows
  const int par  = blockIdx.x & 1;               // col-half processing order

  // stage sequence-slot s (s=0..5): col-half ch = par^(s>=3), pair sp = s%3,
  // into buffer s&1. 8 rounds x 256 threads x 16B, wave-linear.
  auto stage = [&](int s) {
    int ch = par ^ (s >= 3 ? 1 : 0);
    const unsigned short* base = wp + ch * 49152 + (s % 3) * 16384;
#pragma unroll
    for (int i = 0; i < 8; ++i) {
      const unsigned short* g = base + (i * 256 + tid) * 8;
      unsigned short* l = &wlds[s & 1][(i * 256 + wave * 64) * 8];  // HW adds lane*16B
      __builtin_amdgcn_global_load_lds(
          (const __attribute__((address_space(1))) void*)g,
          (__attribute__((address_space(3))) void*)l, 16, 0, 0);
    }
  };

  stage(0);  // in flight while we build xf A-fragments

  // A-fragments: A[m=l15][k=quad*8+j] per 16x16x32 K-tile.
  // xf loaded up front; hf deliberately deferred into phase 0.
  bf16x8 xf[4], hf[4];
  {
    const float* xr = x + (rb + l15) * 128;
#pragma unroll
    for (int kt = 0; kt < 4; ++kt) {
      int off = kt * 32 + quad * 8;
      xf[kt] = cvt8(*(const float4*)(xr + off), *(const float4*)(xr + off + 4));
    }
  }
  float atts[4];
#pragma unroll
  for (int r = 0; r < 4; ++r) atts[r] = att[rb + quad * 4 + r];

  f32x4 accR[4], accH[4], keep[4];

  // one half-matrix gemm: 16 ds_read_b128 + 16 MFMA, wave-linear (0 conflicts)
  auto gemm = [&](int b, int j, const bf16x8 (&af)[4], f32x4 (&acc)[4]) {
#pragma unroll
    for (int nt = 0; nt < 4; ++nt)
#pragma unroll
      for (int kt = 0; kt < 4; ++kt) {
        bf16x8 bfrag = *(const bf16x8*)&wlds[b][j * 8192 + ((nt * 4 + kt) * 64 + lane) * 8];
        acc[nt] = __builtin_amdgcn_mfma_f32_16x16x32_bf16(af[kt], bfrag, acc[nt], 0, 0, 0);
      }
  };
  auto fence = [&]() {
    asm volatile("s_waitcnt vmcnt(0)" ::: "memory");
    __syncthreads();
  };

  fence();  // slot-0 weights + xf resident

  // one col-half = 3 phases; s0 = sequence base (0 or 3), first = load hf here
  auto run_half = [&](int s0, bool first) {
    const int cb = (par ^ (s0 >= 3 ? 1 : 0)) * 64;  // column base
#pragma unroll
    for (int nt = 0; nt < 4; ++nt) { accR[nt] = (f32x4)0.f; accH[nt] = (f32x4)0.f; }

    // --- phase s0: {Wx_r, Wx_h} (xf only; hf loads issued under this phase)
    stage(s0 + 1);
    gemm(s0 & 1, 0, xf, accR);
    gemm(s0 & 1, 1, xf, accH);
    if (first) {
      const float* hr = hp + (rb + l15) * 128;
#pragma unroll
      for (int kt = 0; kt < 4; ++kt) {
        int off = kt * 32 + quad * 8;
        hf[kt] = cvt8(*(const float4*)(hr + off), *(const float4*)(hr + off + 4));
      }
    }
    fence();

    // --- phase s0+1: {Wh_r, Wh_h} -> r, then h_tilde
    stage(s0 + 2);
    gemm((s0 + 1) & 1, 0, hf, accR);   // accR = x.Wx_r + h.Wh_r
#pragma unroll
    for (int nt = 0; nt < 4; ++nt) {
      int col = cb + nt * 16 + l15;
      float br = bx[128 + col] + bh[128 + col];
#pragma unroll
      for (int r = 0; r < 4; ++r) {
        keep[nt][r] = sigmoid_f(accR[nt][r] + br);   // r-gate
        accR[nt][r] = 0.f;
      }
    }
    gemm((s0 + 1) & 1, 1, hf, accR);   // accR = h.Wh_h
#pragma unroll
    for (int nt = 0; nt < 4; ++nt) {
      int col = cb + nt * 16 + l15;
      float bhh = bh[256 + col];
      float bxh = bx[256 + col];
#pragma unroll
      for (int r = 0; r < 4; ++r) {
        // h_tilde = tanh(x.Wx_h + bx_h + r * (h.Wh_h + bh_h))
        keep[nt][r] = tanh_f(accH[nt][r] + bxh + keep[nt][r] * (accR[nt][r] + bhh));
        accR[nt][r] = 0.f;
      }
    }
    fence();

    // --- phase s0+2: {Wx_u, Wh_u} -> u, blend, store this col-half
    if (s0 + 3 < 6) stage(s0 + 3);
    gemm((s0 + 2) & 1, 0, xf, accR);
    gemm((s0 + 2) & 1, 1, hf, accR);
#pragma unroll
    for (int nt = 0; nt < 4; ++nt) {
      int col = cb + nt * 16 + l15;
      float bu = bx[col] + bh[col];
#pragma unroll
      for (int r = 0; r < 4; ++r) {
        int row = rb + quad * 4 + r;
        float u  = sigmoid_f(accR[nt][r] + bu);
        float ua = atts[r] * u;
        float h0 = hp[row * 128 + col];
        out[row * 128 + col] = fmaf(ua, keep[nt][r] - h0, h0);  // (1-ua)*h0+ua*ht
      }
    }
    if (s0 + 3 < 6) fence();
  };

  run_half(0, true);
  run_half(3, false);
}

extern "C" void kernel_launch(void* const* d_in, const int* in_sizes, int n_in,
                              void* d_out, int out_size, void* d_ws, size_t ws_size,
                              hipStream_t stream) {
  const float* x   = (const float*)d_in[0];
  const float* hpv = (const float*)d_in[1];
  const float* att = (const float*)d_in[2];
  const float* Wx  = (const float*)d_in[3];
  const float* bx  = (const float*)d_in[4];
  const float* Wh  = (const float*)d_in[5];
  const float* bh  = (const float*)d_in[6];
  float* out = (float*)d_out;
  unsigned short* wp = (unsigned short*)d_ws;  // 196,608 B of scratch

  pack_weights_kernel<<<48, 256, 0, stream>>>(Wx, Wh, wp);
  augru_kernel<<<1024, 256, 0, stream>>>(x, hpv, att, wp, bx, bh, out);
}